// Round 1
// baseline (413.416 us; speedup 1.0000x reference)
//
#include <hip/hip_runtime.h>
#include <hip/hip_bf16.h>

typedef short v8s __attribute__((ext_vector_type(8)));
typedef float v4f __attribute__((ext_vector_type(4)));

#define DD 128
#define KTOT 64
#define RANK 16

// ws layout (shorts): P~ [0, 131072) | Q~ [131072, 262144) | W~ [262144, 278528)
// P~/Q~ fragment index: (((kg*8+rr)*4+kk)*64 + lane)*8 + j
//   lane=(q*16+c): k=kg*8+(c&7), r=2*rr+(c>>3), d=(kk*4+q)*8+j
// W~ fragment index: ((kg*4+kk)*64 + lane)*8 + j  (c>=8 lanes are zero)
#define QOFF 131072
#define WOFF 262144

__device__ __forceinline__ unsigned int pk_bf16_trunc(float a, float b) {
  return __builtin_amdgcn_perm(__builtin_bit_cast(unsigned int, b),
                               __builtin_bit_cast(unsigned int, a),
                               0x07060302u);
}

__device__ __forceinline__ unsigned short bf16_rne(float x) {
  unsigned int u = __builtin_bit_cast(unsigned int, x);
  u += 0x7FFFu + ((u >> 16) & 1u);
  return (unsigned short)(u >> 16);
}

// async global->LDS, 16B per lane; LDS dest = wave-uniform base + lane*16
__device__ __forceinline__ void stage16(const unsigned short* g, unsigned short* l) {
  __builtin_amdgcn_global_load_lds(
      (const __attribute__((address_space(1))) void*)g,
      (__attribute__((address_space(3))) void*)l, 16, 0, 0);
}

// ---------------- pre-pass: swizzle weights into B-fragment layout ----------
__global__ __launch_bounds__(256)
void swizzle_weights_kernel(const float* __restrict__ Wl,
                            const float* __restrict__ P,
                            const float* __restrict__ Q,
                            unsigned short* __restrict__ ws) {
  const int tid = blockIdx.x * 256 + threadIdx.x;
  if (tid < 16384) {
    // P/Q fragments
    const int kg   = tid >> 11;
    const int rr   = (tid >> 8) & 7;
    const int kk   = (tid >> 6) & 3;
    const int lane = tid & 63;
    const int q = lane >> 4, c = lane & 15;
    const int k = kg * 8 + (c & 7);
    const int r = rr * 2 + (c >> 3);
    const int dbase = (kk * 4 + q) * 8;
    const float* Pg = P + ((long)k * DD) * RANK + r;   // P[k][d][r]
    const float* Qg = Q + ((long)k * DD) * RANK + r;
    union { v8s v; unsigned short h[8]; } po, qo;
#pragma unroll
    for (int j = 0; j < 8; ++j) {
      po.h[j] = bf16_rne(Pg[(long)(dbase + j) * RANK]);
      qo.h[j] = bf16_rne(Qg[(long)(dbase + j) * RANK]);
    }
    *(v8s*)(ws + (long)tid * 8)        = po.v;
    *(v8s*)(ws + QOFF + (long)tid * 8) = qo.v;
  } else if (tid < 16384 + 2048) {
    const int t2   = tid - 16384;
    const int kg   = t2 >> 8;
    const int kk   = (t2 >> 6) & 3;
    const int lane = t2 & 63;
    const int q = lane >> 4, c = lane & 15;
    union { v8s v; unsigned short h[8]; } wo;
#pragma unroll
    for (int j = 0; j < 8; ++j) wo.h[j] = 0;
    if (c < 8) {
      const float* wrow = Wl + (long)(kg * 8 + c) * DD + (kk * 4 + q) * 8;
#pragma unroll
      for (int j = 0; j < 8; ++j) wo.h[j] = bf16_rne(wrow[j]);
    }
    *(v8s*)(ws + WOFF + (long)t2 * 8) = wo.v;
  }
}

// ---------------- main kernel: 512 blocks x 256 rows, all 64 k per block ----
// B-fragments now staged per-kg into LDS (64 KB), shared by the 4 waves:
//   - kg=0 stage overlaps A-fragment build
//   - kg+1 stage overlaps kg epilogue (which touches no LDS)
//   - __syncthreads() vmcnt/lgkm drain retires staging — no explicit waitcnt
__global__ __launch_bounds__(256, 2)
void antisym_bilinear_kernel(const float* __restrict__ x1,
                             const float* __restrict__ x2,
                             const unsigned short* __restrict__ wsw,
                             float* __restrict__ out) {
  __shared__ unsigned short lds[32768];   // P tile [0,16384) | Q tile [16384,32768)

  const int b    = blockIdx.x;      // 512 blocks, 256 rows each
  const int tid  = threadIdx.x;
  const int lane = tid & 63;
  const int wave = tid >> 6;        // 0..3
  const int q    = lane >> 4;
  const int c    = lane & 15;

  const int strip0 = b * 16 + wave * 4;   // 16-row strips; 4 per wave

  // ---- issue kg=0's P/Q stage first: L2 latency hides under the A build
  {
    const unsigned short* gp = wsw + lane * 8;
#pragma unroll
    for (int i = 0; i < 8; ++i) {
      const int ch = (wave * 8 + i) * 512;        // 1 KB chunks, linear
      stage16(gp + ch, lds + ch);
      stage16(gp + QOFF + ch, lds + 16384 + ch);
    }
  }

  // ---- A-fragments (persistent): Z = x1-x2, S = x1+x2, built from global f32
  v8s Zf[4][4], Sf[4][4];
#pragma unroll
  for (int t = 0; t < 4; ++t) {
    const int row = (strip0 + t) * 16 + c;       // A: m = lane&15
    const float4* p1 = (const float4*)(x1 + (long)row * DD);
    const float4* p2 = (const float4*)(x2 + (long)row * DD);
#pragma unroll
    for (int kk = 0; kk < 4; ++kk) {
      const int i0 = kk * 8 + q * 2;             // d0 = kk*32 + q*8
      float4 a0 = p1[i0], a1 = p1[i0 + 1];
      float4 b0 = p2[i0], b1 = p2[i0 + 1];
      union { v8s v; unsigned int u[4]; } z, s;
      z.u[0] = pk_bf16_trunc(a0.x - b0.x, a0.y - b0.y);
      z.u[1] = pk_bf16_trunc(a0.z - b0.z, a0.w - b0.w);
      z.u[2] = pk_bf16_trunc(a1.x - b1.x, a1.y - b1.y);
      z.u[3] = pk_bf16_trunc(a1.z - b1.z, a1.w - b1.w);
      s.u[0] = pk_bf16_trunc(a0.x + b0.x, a0.y + b0.y);
      s.u[1] = pk_bf16_trunc(a0.z + b0.z, a0.w + b0.w);
      s.u[2] = pk_bf16_trunc(a1.x + b1.x, a1.y + b1.y);
      s.u[3] = pk_bf16_trunc(a1.z + b1.z, a1.w + b1.w);
      Zf[t][kk] = z.v;
      Sf[t][kk] = s.v;
    }
  }

  __syncthreads();   // drains kg=0 staging (vmcnt) + barrier

  const unsigned short* lp = lds + lane * 8;

  for (int kg = 0; kg < 8; ++kg) {
    // linear-term W fragments for this kg (global/L2, tiny; used in epilogue)
    v8s Wf[4];
#pragma unroll
    for (int kk = 0; kk < 4; ++kk)
      Wf[kk] = *(const v8s*)(wsw + WOFF + (((long)(kg * 4 + kk) * 64 + lane) * 8));

    v4f acc[4];
#pragma unroll
    for (int t = 0; t < 4; ++t) acc[t] = (v4f){0.f, 0.f, 0.f, 0.f};

#pragma unroll
    for (int rr = 0; rr < 8; ++rr) {
      v8s Pf[4], Qf[4];
#pragma unroll
      for (int kk = 0; kk < 4; ++kk) {
        const int o = ((rr * 4 + kk) * 64) * 8;   // compile-time: ds_read_b128 + imm offset
        Pf[kk] = *(const v8s*)(lp + o);
        Qf[kk] = *(const v8s*)(lp + 16384 + o);
      }
#pragma unroll
      for (int t = 0; t < 4; ++t) {
        v4f ap = (v4f){0.f, 0.f, 0.f, 0.f};
        v4f aq = (v4f){0.f, 0.f, 0.f, 0.f};
#pragma unroll
        for (int kk = 0; kk < 4; ++kk) {
          ap = __builtin_amdgcn_mfma_f32_16x16x32_bf16(Zf[t][kk], Pf[kk], ap, 0, 0, 0);
          aq = __builtin_amdgcn_mfma_f32_16x16x32_bf16(Sf[t][kk], Qf[kk], aq, 0, 0, 0);
        }
        acc[t] += ap * aq;   // matching (row,k,r) pairs: pure VALU, no shuffles
      }
    }

    __syncthreads();   // all waves done READING this kg's LDS tile

    // stage kg+1 now: L2 latency hides under the epilogue below
    if (kg < 7) {
      const unsigned short* gp = wsw + (long)(kg + 1) * 16384 + lane * 8;
#pragma unroll
      for (int i = 0; i < 8; ++i) {
        const int ch = (wave * 8 + i) * 512;
        stage16(gp + ch, lds + ch);
        stage16(gp + QOFF + ch, lds + 16384 + ch);
      }
    }

    // linear term (W cols 8..15 are zero -> lands only in cols 0..7)
#pragma unroll
    for (int t = 0; t < 4; ++t) {
#pragma unroll
      for (int kk = 0; kk < 4; ++kk)
        acc[t] = __builtin_amdgcn_mfma_f32_16x16x32_bf16(Zf[t][kk], Wf[kk], acc[t], 0, 0, 0);
    }

    // epilogue: fold odd-r half (cols 8..15) onto cols 0..7, store 8 floats/row
#pragma unroll
    for (int t = 0; t < 4; ++t) {
      float v0 = acc[t][0], v1 = acc[t][1], v2 = acc[t][2], v3 = acc[t][3];
      v0 += __shfl_xor(v0, 8, 64);
      v1 += __shfl_xor(v1, 8, 64);
      v2 += __shfl_xor(v2, 8, 64);
      v3 += __shfl_xor(v3, 8, 64);
      const int row0 = (strip0 + t) * 16 + q * 4;  // C: row = quad*4 + reg
      const int cc = c & 7;
      float* op = out + (long)row0 * KTOT + kg * 8 + cc;
      if (c < 8) { op[0 * KTOT] = v0; op[1 * KTOT] = v1; }
      else       { op[2 * KTOT] = v2; op[3 * KTOT] = v3; }
    }

    __syncthreads();   // staged kg+1 retired (vmcnt drain) before next reads
  }
}

extern "C" void kernel_launch(void* const* d_in, const int* in_sizes, int n_in,
                              void* d_out, int out_size, void* d_ws, size_t ws_size,
                              hipStream_t stream) {
  (void)in_sizes; (void)n_in; (void)ws_size; (void)out_size;
  const float* x1 = (const float*)d_in[0];
  const float* x2 = (const float*)d_in[1];
  const float* Wl = (const float*)d_in[2];
  const float* P  = (const float*)d_in[3];
  const float* Q  = (const float*)d_in[4];
  float* out = (float*)d_out;
  unsigned short* ws = (unsigned short*)d_ws;   // needs 544 KB

  hipLaunchKernelGGL(swizzle_weights_kernel, dim3(72), dim3(256), 0, stream,
                     Wl, P, Q, ws);
  hipLaunchKernelGGL(antisym_bilinear_kernel, dim3(512), dim3(256), 0, stream,
                     x1, x2, ws, out);
}

// Round 2
// 218.329 us; speedup vs baseline: 1.8936x; 1.8936x over previous
//
#include <hip/hip_runtime.h>
#include <hip/hip_bf16.h>

typedef short v8s __attribute__((ext_vector_type(8)));
typedef float v4f __attribute__((ext_vector_type(4)));

#define DD 128
#define KTOT 64
#define RANK 16

// ws layout (shorts):
//   per kg (kg=0..7): P_kg at [kg*32768, kg*32768+16384) | Q_kg at [+16384, +32768)
//   W~ at [262144, 278528)
// P/Q fragment index within kg: ((rr*4+kk)*64 + lane)*8 + j
//   lane=(q*16+c): k=kg*8+(c&7), r=2*rr+(c>>3), d=(kk*4+q)*8+j
// W~ fragment index: ((kg*4+kk)*64 + lane)*8 + j  (c>=8 lanes are zero)
#define WOFF 262144

__device__ __forceinline__ unsigned int pk_bf16_trunc(float a, float b) {
  return __builtin_amdgcn_perm(__builtin_bit_cast(unsigned int, b),
                               __builtin_bit_cast(unsigned int, a),
                               0x07060302u);
}

__device__ __forceinline__ unsigned short bf16_rne(float x) {
  unsigned int u = __builtin_bit_cast(unsigned int, x);
  u += 0x7FFFu + ((u >> 16) & 1u);
  return (unsigned short)(u >> 16);
}

// async global->LDS, 16B per lane; LDS dest = wave-uniform base + lane*16
__device__ __forceinline__ void stage16(const unsigned short* g, unsigned short* l) {
  __builtin_amdgcn_global_load_lds(
      (const __attribute__((address_space(1))) void*)g,
      (__attribute__((address_space(3))) void*)l, 16, 0, 0);
}

// ---------------- pre-pass: swizzle weights into B-fragment layout ----------
__global__ __launch_bounds__(256)
void swizzle_weights_kernel(const float* __restrict__ Wl,
                            const float* __restrict__ P,
                            const float* __restrict__ Q,
                            unsigned short* __restrict__ ws) {
  const int tid = blockIdx.x * 256 + threadIdx.x;
  if (tid < 16384) {
    // P/Q fragments
    const int kg    = tid >> 11;
    const int local = tid & 2047;          // (rr*4+kk)*64 + lane
    const int rr    = (tid >> 8) & 7;
    const int kk    = (tid >> 6) & 3;
    const int lane  = tid & 63;
    const int q = lane >> 4, c = lane & 15;
    const int k = kg * 8 + (c & 7);
    const int r = rr * 2 + (c >> 3);
    const int dbase = (kk * 4 + q) * 8;
    const float* Pg = P + ((long)k * DD) * RANK + r;   // P[k][d][r]
    const float* Qg = Q + ((long)k * DD) * RANK + r;
    union { v8s v; unsigned short h[8]; } po, qo;
#pragma unroll
    for (int j = 0; j < 8; ++j) {
      po.h[j] = bf16_rne(Pg[(long)(dbase + j) * RANK]);
      qo.h[j] = bf16_rne(Qg[(long)(dbase + j) * RANK]);
    }
    *(v8s*)(ws + (long)kg * 32768 + (long)local * 8)         = po.v;
    *(v8s*)(ws + (long)kg * 32768 + 16384 + (long)local * 8) = qo.v;
  } else if (tid < 16384 + 2048) {
    const int t2   = tid - 16384;
    const int kg   = t2 >> 8;
    const int kk   = (t2 >> 6) & 3;
    const int lane = t2 & 63;
    const int q = lane >> 4, c = lane & 15;
    union { v8s v; unsigned short h[8]; } wo;
#pragma unroll
    for (int j = 0; j < 8; ++j) wo.h[j] = 0;
    if (c < 8) {
      const float* wrow = Wl + (long)(kg * 8 + c) * DD + (kk * 4 + q) * 8;
#pragma unroll
      for (int j = 0; j < 8; ++j) wo.h[j] = bf16_rne(wrow[j]);
    }
    *(v8s*)(ws + WOFF + (long)t2 * 8) = wo.v;
  }
}

// ---------------- main kernel: 512 blocks x 512 threads, 256 rows/block -----
// 8 waves x 2 strips/wave: Zf/Sf = 64 VGPRs (was 128 -> spilled).
// B-tiles double-buffered in LDS (2 x 64 KB); kg+1 staged at top of kg,
// retired by the end-of-kg __syncthreads (full vmcnt drain) — m97 pattern.
__global__ __launch_bounds__(512, 2)
void antisym_bilinear_kernel(const float* __restrict__ x1,
                             const float* __restrict__ x2,
                             const unsigned short* __restrict__ wsw,
                             float* __restrict__ out) {
  __shared__ unsigned short lds[2][32768];   // per buf: P [0,16384) | Q [16384,32768)

  const int b    = blockIdx.x;      // 512 blocks, 256 rows each
  const int tid  = threadIdx.x;
  const int lane = tid & 63;
  const int wave = tid >> 6;        // 0..7
  const int q    = lane >> 4;
  const int c    = lane & 15;

  const int strip0 = b * 16 + wave * 2;   // 16-row strips; 2 per wave

  // ---- issue kg=0's P/Q stage first: latency hides under the A build
  {
    const unsigned short* gp = wsw + lane * 8;
#pragma unroll
    for (int i = 0; i < 8; ++i) {
      const int ch = (wave * 8 + i) * 512;        // 64 x 1 KB chunks, linear
      stage16(gp + ch, &lds[0][0] + ch);
    }
  }

  // ---- A-fragments (persistent): Z = x1-x2, S = x1+x2, built from global f32
  v8s Zf[2][4], Sf[2][4];
#pragma unroll
  for (int t = 0; t < 2; ++t) {
    const int row = (strip0 + t) * 16 + c;       // A: m = lane&15
    const float4* p1 = (const float4*)(x1 + (long)row * DD);
    const float4* p2 = (const float4*)(x2 + (long)row * DD);
#pragma unroll
    for (int kk = 0; kk < 4; ++kk) {
      const int i0 = kk * 8 + q * 2;             // d0 = kk*32 + q*8
      float4 a0 = p1[i0], a1 = p1[i0 + 1];
      float4 b0 = p2[i0], b1 = p2[i0 + 1];
      union { v8s v; unsigned int u[4]; } z, s;
      z.u[0] = pk_bf16_trunc(a0.x - b0.x, a0.y - b0.y);
      z.u[1] = pk_bf16_trunc(a0.z - b0.z, a0.w - b0.w);
      z.u[2] = pk_bf16_trunc(a1.x - b1.x, a1.y - b1.y);
      z.u[3] = pk_bf16_trunc(a1.z - b1.z, a1.w - b1.w);
      s.u[0] = pk_bf16_trunc(a0.x + b0.x, a0.y + b0.y);
      s.u[1] = pk_bf16_trunc(a0.z + b0.z, a0.w + b0.w);
      s.u[2] = pk_bf16_trunc(a1.x + b1.x, a1.y + b1.y);
      s.u[3] = pk_bf16_trunc(a1.z + b1.z, a1.w + b1.w);
      Zf[t][kk] = z.v;
      Sf[t][kk] = s.v;
    }
  }

  __syncthreads();   // drains kg=0 staging (vmcnt) + barrier

  for (int kg = 0; kg < 8; ++kg) {
    // stage kg+1 into the other buffer; retires under this kg's compute
    if (kg < 7) {
      const unsigned short* gp = wsw + (long)(kg + 1) * 32768 + lane * 8;
      unsigned short* lbase = &lds[(kg + 1) & 1][0];
#pragma unroll
      for (int i = 0; i < 8; ++i) {
        const int ch = (wave * 8 + i) * 512;
        stage16(gp + ch, lbase + ch);
      }
    }

    // linear-term W fragments for this kg (global/L2, tiny; used late)
    v8s Wf[4];
#pragma unroll
    for (int kk = 0; kk < 4; ++kk)
      Wf[kk] = *(const v8s*)(wsw + WOFF + (((long)(kg * 4 + kk) * 64 + lane) * 8));

    const unsigned short* lp = &lds[kg & 1][0] + lane * 8;

    v4f acc[2];
#pragma unroll
    for (int t = 0; t < 2; ++t) acc[t] = (v4f){0.f, 0.f, 0.f, 0.f};

#pragma unroll
    for (int rr = 0; rr < 8; ++rr) {
      v8s Pf[4], Qf[4];
#pragma unroll
      for (int kk = 0; kk < 4; ++kk) {
        const int o = (rr * 4 + kk) * 512;        // compile-time ds offsets
        Pf[kk] = *(const v8s*)(lp + o);
        Qf[kk] = *(const v8s*)(lp + 16384 + o);
      }
#pragma unroll
      for (int t = 0; t < 2; ++t) {
        v4f ap = (v4f){0.f, 0.f, 0.f, 0.f};
        v4f aq = (v4f){0.f, 0.f, 0.f, 0.f};
#pragma unroll
        for (int kk = 0; kk < 4; ++kk) {
          ap = __builtin_amdgcn_mfma_f32_16x16x32_bf16(Zf[t][kk], Pf[kk], ap, 0, 0, 0);
          aq = __builtin_amdgcn_mfma_f32_16x16x32_bf16(Sf[t][kk], Qf[kk], aq, 0, 0, 0);
        }
        acc[t] += ap * aq;   // matching (row,k,r) pairs: pure VALU, no shuffles
      }
    }

    // linear term (W cols 8..15 are zero -> lands only in cols 0..7)
#pragma unroll
    for (int t = 0; t < 2; ++t) {
#pragma unroll
      for (int kk = 0; kk < 4; ++kk)
        acc[t] = __builtin_amdgcn_mfma_f32_16x16x32_bf16(Zf[t][kk], Wf[kk], acc[t], 0, 0, 0);
    }

    // epilogue: fold odd-r half (cols 8..15) onto cols 0..7, store 8 floats/row
#pragma unroll
    for (int t = 0; t < 2; ++t) {
      float v0 = acc[t][0], v1 = acc[t][1], v2 = acc[t][2], v3 = acc[t][3];
      v0 += __shfl_xor(v0, 8, 64);
      v1 += __shfl_xor(v1, 8, 64);
      v2 += __shfl_xor(v2, 8, 64);
      v3 += __shfl_xor(v3, 8, 64);
      const int row0 = (strip0 + t) * 16 + q * 4;  // C: row = quad*4 + reg
      const int cc = c & 7;
      float* op = out + (long)row0 * KTOT + kg * 8 + cc;
      if (c < 8) { op[0 * KTOT] = v0; op[1 * KTOT] = v1; }
      else       { op[2 * KTOT] = v2; op[3 * KTOT] = v3; }
    }

    __syncthreads();   // all waves done with buf[kg&1]; staged kg+1 retired
  }
}

extern "C" void kernel_launch(void* const* d_in, const int* in_sizes, int n_in,
                              void* d_out, int out_size, void* d_ws, size_t ws_size,
                              hipStream_t stream) {
  (void)in_sizes; (void)n_in; (void)ws_size; (void)out_size;
  const float* x1 = (const float*)d_in[0];
  const float* x2 = (const float*)d_in[1];
  const float* Wl = (const float*)d_in[2];
  const float* P  = (const float*)d_in[3];
  const float* Q  = (const float*)d_in[4];
  float* out = (float*)d_out;
  unsigned short* ws = (unsigned short*)d_ws;   // needs 544 KB

  hipLaunchKernelGGL(swizzle_weights_kernel, dim3(72), dim3(256), 0, stream,
                     Wl, P, Q, ws);
  hipLaunchKernelGGL(antisym_bilinear_kernel, dim3(512), dim3(512), 0, stream,
                     x1, x2, ws, out);
}

// Round 3
// 214.692 us; speedup vs baseline: 1.9256x; 1.0169x over previous
//
#include <hip/hip_runtime.h>
#include <hip/hip_bf16.h>

typedef short v8s __attribute__((ext_vector_type(8)));
typedef float v4f __attribute__((ext_vector_type(4)));

#define DD 128
#define KTOT 64
#define RANK 16

// ws layout (shorts):
//   per kg (kg=0..7): P_kg at [kg*32768, kg*32768+16384) | Q_kg at [+16384, +32768)
//   W~ at [262144, 278528)
// P/Q fragment index within kg: ((rr*4+kk)*64 + lane)*8 + j
//   lane=(q*16+c): k=kg*8+(c&7), r=2*rr+(c>>3), d=(kk*4+q)*8+j
// W~ fragment index: ((kg*4+kk)*64 + lane)*8 + j  (c>=8 lanes are zero)
#define WOFF 262144

__device__ __forceinline__ unsigned int pk_bf16_trunc(float a, float b) {
  return __builtin_amdgcn_perm(__builtin_bit_cast(unsigned int, b),
                               __builtin_bit_cast(unsigned int, a),
                               0x07060302u);
}

__device__ __forceinline__ unsigned short bf16_rne(float x) {
  unsigned int u = __builtin_bit_cast(unsigned int, x);
  u += 0x7FFFu + ((u >> 16) & 1u);
  return (unsigned short)(u >> 16);
}

// async global->LDS, 16B per lane; LDS dest = wave-uniform base + lane*16
__device__ __forceinline__ void stage16(const unsigned short* g, unsigned short* l) {
  __builtin_amdgcn_global_load_lds(
      (const __attribute__((address_space(1))) void*)g,
      (__attribute__((address_space(3))) void*)l, 16, 0, 0);
}

// ---------------- pre-pass: swizzle weights into B-fragment layout ----------
__global__ __launch_bounds__(256)
void swizzle_weights_kernel(const float* __restrict__ Wl,
                            const float* __restrict__ P,
                            const float* __restrict__ Q,
                            unsigned short* __restrict__ ws) {
  const int tid = blockIdx.x * 256 + threadIdx.x;
  if (tid < 16384) {
    // P/Q fragments
    const int kg    = tid >> 11;
    const int local = tid & 2047;          // (rr*4+kk)*64 + lane
    const int rr    = (tid >> 8) & 7;
    const int kk    = (tid >> 6) & 3;
    const int lane  = tid & 63;
    const int q = lane >> 4, c = lane & 15;
    const int k = kg * 8 + (c & 7);
    const int r = rr * 2 + (c >> 3);
    const int dbase = (kk * 4 + q) * 8;
    const float* Pg = P + ((long)k * DD) * RANK + r;   // P[k][d][r]
    const float* Qg = Q + ((long)k * DD) * RANK + r;
    union { v8s v; unsigned short h[8]; } po, qo;
#pragma unroll
    for (int j = 0; j < 8; ++j) {
      po.h[j] = bf16_rne(Pg[(long)(dbase + j) * RANK]);
      qo.h[j] = bf16_rne(Qg[(long)(dbase + j) * RANK]);
    }
    *(v8s*)(ws + (long)kg * 32768 + (long)local * 8)         = po.v;
    *(v8s*)(ws + (long)kg * 32768 + 16384 + (long)local * 8) = qo.v;
  } else if (tid < 16384 + 2048) {
    const int t2   = tid - 16384;
    const int kg   = t2 >> 8;
    const int kk   = (t2 >> 6) & 3;
    const int lane = t2 & 63;
    const int q = lane >> 4, c = lane & 15;
    union { v8s v; unsigned short h[8]; } wo;
#pragma unroll
    for (int j = 0; j < 8; ++j) wo.h[j] = 0;
    if (c < 8) {
      const float* wrow = Wl + (long)(kg * 8 + c) * DD + (kk * 4 + q) * 8;
#pragma unroll
      for (int j = 0; j < 8; ++j) wo.h[j] = bf16_rne(wrow[j]);
    }
    *(v8s*)(ws + WOFF + (long)t2 * 8) = wo.v;
  }
}

// ---------------- main kernel: 256 blocks x 512 threads, 512 rows/block -----
// One block per CU (no second round). 8 waves x 4 strips/wave:
//   - per-output LDS-read traffic halved vs 2-strip version
//   - prologue (A-build) paid once per CU instead of twice
// B-tiles double-buffered in LDS (2 x 64 KB); kg+1 staged at top of kg,
// retired by the end-of-kg __syncthreads (full vmcnt drain).
// VGPR budget: Zf/Sf 128 + Pf/Qf 32 + Wf 16 + acc 16 + temps ~ 220 < 256.
__global__ __launch_bounds__(512, 2)
void antisym_bilinear_kernel(const float* __restrict__ x1,
                             const float* __restrict__ x2,
                             const unsigned short* __restrict__ wsw,
                             float* __restrict__ out) {
  __shared__ unsigned short lds[2][32768];   // per buf: P [0,16384) | Q [16384,32768)

  const int b    = blockIdx.x;      // 256 blocks, 512 rows each
  const int tid  = threadIdx.x;
  const int lane = tid & 63;
  const int wave = tid >> 6;        // 0..7
  const int q    = lane >> 4;
  const int c    = lane & 15;

  const int strip0 = b * 32 + wave * 4;   // 16-row strips; 4 per wave

  // ---- issue kg=0's P/Q stage first: latency hides under the A build
  {
    const unsigned short* gp = wsw + lane * 8;
#pragma unroll
    for (int i = 0; i < 8; ++i) {
      const int ch = (wave * 8 + i) * 512;        // 64 x 1 KB chunks, linear
      stage16(gp + ch, &lds[0][0] + ch);
    }
  }

  // ---- A-fragments (persistent): Z = x1-x2, S = x1+x2, built from global f32
  // One strip at a time + compiler fence: bounds in-flight temps (~64 regs)
  // so the allocator never sees 256 live loads (round-0 spill trigger).
  v8s Zf[4][4], Sf[4][4];
#pragma unroll
  for (int t = 0; t < 4; ++t) {
    const int row = (strip0 + t) * 16 + c;       // A: m = lane&15
    const float4* p1 = (const float4*)(x1 + (long)row * DD);
    const float4* p2 = (const float4*)(x2 + (long)row * DD);
#pragma unroll
    for (int kk = 0; kk < 4; ++kk) {
      const int i0 = kk * 8 + q * 2;             // d0 = kk*32 + q*8
      float4 a0 = p1[i0], a1 = p1[i0 + 1];
      float4 b0 = p2[i0], b1 = p2[i0 + 1];
      union { v8s v; unsigned int u[4]; } z, s;
      z.u[0] = pk_bf16_trunc(a0.x - b0.x, a0.y - b0.y);
      z.u[1] = pk_bf16_trunc(a0.z - b0.z, a0.w - b0.w);
      z.u[2] = pk_bf16_trunc(a1.x - b1.x, a1.y - b1.y);
      z.u[3] = pk_bf16_trunc(a1.z - b1.z, a1.w - b1.w);
      s.u[0] = pk_bf16_trunc(a0.x + b0.x, a0.y + b0.y);
      s.u[1] = pk_bf16_trunc(a0.z + b0.z, a0.w + b0.w);
      s.u[2] = pk_bf16_trunc(a1.x + b1.x, a1.y + b1.y);
      s.u[3] = pk_bf16_trunc(a1.z + b1.z, a1.w + b1.w);
      Zf[t][kk] = z.v;
      Sf[t][kk] = s.v;
    }
    asm volatile("" ::: "memory");   // don't hoist next strip's loads
  }

  __syncthreads();   // drains kg=0 staging (vmcnt) + barrier

  for (int kg = 0; kg < 8; ++kg) {
    // stage kg+1 into the other buffer; retires under this kg's compute
    if (kg < 7) {
      const unsigned short* gp = wsw + (long)(kg + 1) * 32768 + lane * 8;
      unsigned short* lbase = &lds[(kg + 1) & 1][0];
#pragma unroll
      for (int i = 0; i < 8; ++i) {
        const int ch = (wave * 8 + i) * 512;
        stage16(gp + ch, lbase + ch);
      }
    }

    // linear-term W fragments for this kg (global/L2, tiny; used late)
    v8s Wf[4];
#pragma unroll
    for (int kk = 0; kk < 4; ++kk)
      Wf[kk] = *(const v8s*)(wsw + WOFF + (((long)(kg * 4 + kk) * 64 + lane) * 8));

    const unsigned short* lp = &lds[kg & 1][0] + lane * 8;

    v4f acc[4];
#pragma unroll
    for (int t = 0; t < 4; ++t) acc[t] = (v4f){0.f, 0.f, 0.f, 0.f};

#pragma unroll
    for (int rr = 0; rr < 8; ++rr) {
      v8s Pf[4], Qf[4];
#pragma unroll
      for (int kk = 0; kk < 4; ++kk) {
        const int o = (rr * 4 + kk) * 512;        // compile-time ds offsets
        Pf[kk] = *(const v8s*)(lp + o);
        Qf[kk] = *(const v8s*)(lp + 16384 + o);
      }
#pragma unroll
      for (int t = 0; t < 4; ++t) {
        v4f ap = (v4f){0.f, 0.f, 0.f, 0.f};
        v4f aq = (v4f){0.f, 0.f, 0.f, 0.f};
#pragma unroll
        for (int kk = 0; kk < 4; ++kk) {
          ap = __builtin_amdgcn_mfma_f32_16x16x32_bf16(Zf[t][kk], Pf[kk], ap, 0, 0, 0);
          aq = __builtin_amdgcn_mfma_f32_16x16x32_bf16(Sf[t][kk], Qf[kk], aq, 0, 0, 0);
        }
        acc[t] += ap * aq;   // matching (row,k,r) pairs: pure VALU, no shuffles
      }
    }

    // linear term (W cols 8..15 are zero -> lands only in cols 0..7)
#pragma unroll
    for (int t = 0; t < 4; ++t) {
#pragma unroll
      for (int kk = 0; kk < 4; ++kk)
        acc[t] = __builtin_amdgcn_mfma_f32_16x16x32_bf16(Zf[t][kk], Wf[kk], acc[t], 0, 0, 0);
    }

    // epilogue: fold odd-r half (cols 8..15) onto cols 0..7, store 8 floats/row
#pragma unroll
    for (int t = 0; t < 4; ++t) {
      float v0 = acc[t][0], v1 = acc[t][1], v2 = acc[t][2], v3 = acc[t][3];
      v0 += __shfl_xor(v0, 8, 64);
      v1 += __shfl_xor(v1, 8, 64);
      v2 += __shfl_xor(v2, 8, 64);
      v3 += __shfl_xor(v3, 8, 64);
      const int row0 = (strip0 + t) * 16 + q * 4;  // C: row = quad*4 + reg
      const int cc = c & 7;
      float* op = out + (long)row0 * KTOT + kg * 8 + cc;
      if (c < 8) { op[0 * KTOT] = v0; op[1 * KTOT] = v1; }
      else       { op[2 * KTOT] = v2; op[3 * KTOT] = v3; }
    }

    __syncthreads();   // all waves done with buf[kg&1]; staged kg+1 retired
  }
}

extern "C" void kernel_launch(void* const* d_in, const int* in_sizes, int n_in,
                              void* d_out, int out_size, void* d_ws, size_t ws_size,
                              hipStream_t stream) {
  (void)in_sizes; (void)n_in; (void)ws_size; (void)out_size;
  const float* x1 = (const float*)d_in[0];
  const float* x2 = (const float*)d_in[1];
  const float* Wl = (const float*)d_in[2];
  const float* P  = (const float*)d_in[3];
  const float* Q  = (const float*)d_in[4];
  float* out = (float*)d_out;
  unsigned short* ws = (unsigned short*)d_ws;   // needs 544 KB

  hipLaunchKernelGGL(swizzle_weights_kernel, dim3(72), dim3(256), 0, stream,
                     Wl, P, Q, ws);
  hipLaunchKernelGGL(antisym_bilinear_kernel, dim3(256), dim3(512), 0, stream,
                     x1, x2, ws, out);
}